// Round 12
// baseline (62.367 us; speedup 1.0000x reference)
//
#include <hip/hip_runtime.h>

typedef __attribute__((ext_vector_type(8))) short bf16x8;
typedef __attribute__((ext_vector_type(4))) float f32x4;

#define EPSV 1e-5f
// (1/TEMP) * log2(e),  TEMP = 0.5  -> exp2-domain scale
#define SCALE 2.885390081777927f

// Must be the builtin — raw inline-asm v_exp_f32 lacks the TRANS-pipe hazard
// nop (asm is opaque to the hazard recognizer) and returns garbage (R4).
__device__ __forceinline__ float fast_exp2(float x) { return __builtin_amdgcn_exp2f(x); }

// async global->LDS DMA, 16 B per lane; LDS dest = uniform base + lane*16.
__device__ __forceinline__ void dma16(const void* g, void* l) {
  __builtin_amdgcn_global_load_lds(
      (const __attribute__((address_space(1))) unsigned*)g,
      (__attribute__((address_space(3))) unsigned*)l, 16, 0, 0);
}

__device__ __forceinline__ ushort f32_to_bf16(float f) {
  union { float f; unsigned u; } cv; cv.f = f;
  unsigned u = cv.u;
  u += 0x7FFFu + ((u >> 16) & 1u);   // round-to-nearest-even
  return (ushort)(u >> 16);
}

// ---------------------------------------------------------------------------
// Packed bank layout (bf16, pre-scaled by SCALE):
//   col-tile ct = col>>4, r16 = col&15; channel c: ks = c>>5, kg = (c>>3)&3.
//   byte addr = ct*8192 + ks*1024 + kg*256 + r16*16 + (c&7)*2
// Per col-range the 512-col stream is LINEAR; staged in 4 KB quarters
// (16 cols x 128 K each; two quarters = one col-tile).
// ---------------------------------------------------------------------------

// ---------------------------------------------------------------------------
// Fused prep kernel, grid = 512 + 512 + 64 = 1088 blocks, 256 threads.
// ---------------------------------------------------------------------------
__global__ __launch_bounds__(256) void cpl_prep(
    const float* __restrict__ mainO, const float* __restrict__ emaO,
    const float* __restrict__ label, const float* __restrict__ negB,
    const float* __restrict__ posB,
    ushort* __restrict__ Apk, float* __restrict__ posDot,
    int* __restrict__ flags, ushort* __restrict__ bankN, ushort* __restrict__ bankP)
{
  __shared__ ushort shU[64 * 256];   // 32 KiB
  __shared__ float  shF[4][64];
  const int bid = blockIdx.x;
  const int t = threadIdx.x;

  if (bid < 512) {
    // ---- anchor pack + pos dot: block = (b, y) ----
    const int b = bid >> 6, y = bid & 63;
    const int cg = t >> 4;            // c-offset 0..15
    const int x4 = t & 15;            // float4 index along W
    const float* mB = mainO + (((size_t)b * 256 + cg) * 64 + y) * 64 + x4 * 4;
    const float* eB = emaO  + (((size_t)b * 256 + cg) * 64 + y) * 64 + x4 * 4;
    float4 acc4 = make_float4(0.f, 0.f, 0.f, 0.f);
#pragma unroll
    for (int pass = 0; pass < 16; ++pass) {
      const int c = pass * 16 + cg;
      const float4 mv = *(const float4*)(mB + (size_t)pass * 16 * 4096);
      const float4 ev = *(const float4*)(eB + (size_t)pass * 16 * 4096);
      acc4.x += mv.x * ev.x; acc4.y += mv.y * ev.y;
      acc4.z += mv.z * ev.z; acc4.w += mv.w * ev.w;
      const float vals[4] = {mv.x, mv.y, mv.z, mv.w};
#pragma unroll
      for (int j = 0; j < 4; ++j) {
        const int x = x4 * 4 + j;
        shU[x * 256 + (c ^ ((x & 7) << 3))] = f32_to_bf16(vals[j]);
      }
    }
    // reduce pos partials over c-groups (cg bit0 = lane bit4, bit1 = lane bit5)
    acc4.x += __shfl_xor(acc4.x, 16, 64); acc4.y += __shfl_xor(acc4.y, 16, 64);
    acc4.z += __shfl_xor(acc4.z, 16, 64); acc4.w += __shfl_xor(acc4.w, 16, 64);
    acc4.x += __shfl_xor(acc4.x, 32, 64); acc4.y += __shfl_xor(acc4.y, 32, 64);
    acc4.z += __shfl_xor(acc4.z, 32, 64); acc4.w += __shfl_xor(acc4.w, 32, 64);
    if ((t & 63) < 16) *(float4*)&shF[t >> 6][(t & 15) * 4] = acc4;
    __syncthreads();
    // write packed anchors (coalesced b128)
#pragma unroll
    for (int it = 0; it < 8; ++it) {
      const int lin = it * 256 + t;          // 0..2047
      const int x = lin >> 5, c8 = lin & 31;
      const uint4 v = *(const uint4*)&shU[x * 256 + ((c8 * 8) ^ ((x & 7) << 3))];
      const int p = b * 64 + ((y >> 3) << 3) + (x >> 3);
      const int n = ((y & 7) << 3) + (x & 7);
      *(uint4*)&Apk[((size_t)p * 64 + n) * 256 + c8 * 8] = v;
    }
    if (t < 64) {
      const float pv = shF[0][t] + shF[1][t] + shF[2][t] + shF[3][t];
      const int p = b * 64 + ((y >> 3) << 3) + (t >> 3);
      const int n = ((y & 7) << 3) + (t & 7);
      posDot[p * 64 + n] = pv;
    }
  } else if (bid < 1024) {
    // ---- label mean -> flag ----
    const int p = bid - 512;
    const int b = p >> 6, pj = (p >> 3) & 7, pk = p & 7;
    const size_t base = ((size_t)b * 256 + pj * 32) * 256 + pk * 32;
    float s = 0.f;
#pragma unroll
    for (int i = 0; i < 4; ++i) {
      const int e = t * 4 + i;               // 0..1023, r=e>>5, cc=e&31
      s += label[base + (size_t)(e >> 5) * 256 + (e & 31)];
    }
#pragma unroll
    for (int d = 1; d < 64; d <<= 1) s += __shfl_xor(s, d, 64);
    if ((t & 63) == 0) shF[0][t >> 6] = s;
    __syncthreads();
    if (t == 0)
      flags[p] = ((shF[0][0] + shF[0][1] + shF[0][2] + shF[0][3]) * (1.f / 1024.f) < 0.1f) ? 1 : 0;
  } else {
    // ---- bank repack (pre-scaled by SCALE) into the packed tile layout ----
    const int bb = bid - 1024;
    const float* src = (bb < 32 ? negB : posB) + (size_t)(bb & 31) * 16384;
    ushort* dst = (bb < 32 ? bankN : bankP) + (size_t)(bb & 31) * 16384;
#pragma unroll 8
    for (int it = 0; it < 64; ++it) {
      const int lin = it * 256 + t;          // [c][posi] linear, coalesced read
      const int c = lin >> 6, posi = lin & 63;
      shU[(posi * 256 + c) ^ ((posi & 31) << 1)] = f32_to_bf16(src[lin] * SCALE);
    }
    __syncthreads();
    unsigned* dst32 = (unsigned*)dst;        // 8192 uints per slab
#pragma unroll 8
    for (int it = 0; it < 32; ++it) {
      const int pt = it >> 3, ks = it & 7;
      const int kg = t >> 6, r16 = (t >> 2) & 15, bw = t & 3;
      const int posi = pt * 16 + r16;
      const int c = ks * 32 + kg * 8 + bw * 2;
      const unsigned v = *(const unsigned*)&shU[(posi * 256 + c) ^ ((posi & 31) << 1)];
      dst32[pt * 2048 + ks * 256 + kg * 64 + r16 * 4 + bw] = v;
    }
  }
}

// ---------------------------------------------------------------------------
// Main kernel: grid=512 (one patch), block=256 (4 independent waves).
// Dependency-decoupled pipeline: per step, ds_read prefetches NEXT quarter
// into the spare bfrag register buffer (latency hidden under MFMA), MFMAs
// consume registers loaded LAST step, and EXP of the PREVIOUS tile's acc
// (separate acc buffer -> no WAR) interleaves with the MFMA cluster on the
// TRANS pipe. No __syncthreads; counted vmcnt; per-block phase stagger.
// ---------------------------------------------------------------------------
__global__ __launch_bounds__(256, 2) void cpl_main(
    const ushort* __restrict__ Apk, const float* __restrict__ posDot,
    const ushort* __restrict__ bankN, const ushort* __restrict__ bankP,
    const int* __restrict__ flags, float* __restrict__ blockSums)
{
  __shared__ __align__(1024) char Bsm[4 * 16384];   // 4 waves x 4-deep ring
  __shared__ float swS[4][64];

  const int p = blockIdx.x;
  const int t = threadIdx.x;
  const int l = t & 63, w = t >> 6;
  const int r16 = l & 15, kg = l >> 4;
  const int qph = (p * 11) & 63;      // per-block traversal phase

  const char* bankB = (const char*)(flags[p] ? bankP : bankN);
  const char* wsrc = bankB + (size_t)w * 262144;     // wave's 512-col stream
  char* wlds = Bsm + w * 16384;
  const int lofs = l * 16;

  // ---- A fragments: lane l holds A[mt*16+(l&15)][ks*32+(l>>4)*8 + 0..7] ----
  const ushort* Ab = Apk + (size_t)p * 16384;
  bf16x8 afrag[4][8];
#pragma unroll
  for (int mt = 0; mt < 4; ++mt)
#pragma unroll
    for (int ks = 0; ks < 8; ++ks)
      afrag[mt][ks] = *(const bf16x8*)(Ab + (mt * 16 + r16) * 256 + ks * 32 + kg * 8);
#pragma unroll
  for (int mt = 0; mt < 4; ++mt)
#pragma unroll
    for (int ks = 0; ks < 8; ++ks)
      asm volatile("" : "+v"(afrag[mt][ks]));

  // per-lane -pos2 init in REGISTERS (row = mt*16 + kg*4 + i), direct global
  f32x4 negInit[4];
#pragma unroll
  for (int mt = 0; mt < 4; ++mt) {
    f32x4 v = *(const f32x4*)(posDot + (size_t)p * 64 + mt * 16 + kg * 4);
#pragma unroll
    for (int i = 0; i < 4; ++i) negInit[mt][i] = -v[i] * SCALE;
  }
#pragma unroll
  for (int mt = 0; mt < 4; ++mt) asm volatile("" : "+v"(negInit[mt]));

  // drain prologue loads so vmcnt counting below is clean
  asm volatile("s_waitcnt vmcnt(0)" ::: "memory");

#define ISSUEQ(QQ) do {                                                            \
    const char* g0_ = wsrc + (size_t)((((QQ) + qph) & 63)) * 4096 + lofs;          \
    char* l0_ = wlds + ((QQ) & 3) * 4096;                                          \
    _Pragma("unroll") for (int i = 0; i < 4; ++i)                                  \
      dma16(g0_ + i * 1024, l0_ + i * 1024);                                       \
  } while (0)

  float s[16];
#pragma unroll
  for (int e = 0; e < 16; ++e) s[e] = 0.f;

  f32x4 accA[4], accB[4];
  bf16x8 bfE[4], bfO[4];
  const char* rbase = wlds + kg * 256 + r16 * 16;

#define DSREAD(BF, SLOT) do {                                                      \
    const char* rb_ = rbase + (SLOT) * 4096;                                       \
    _Pragma("unroll") for (int k = 0; k < 4; ++k)                                  \
      BF[k] = *(const bf16x8*)(rb_ + k * 1024);                                    \
  } while (0)

  // EXP half IH (i = 2*IH, 2*IH+1) of ACCV into s
#define EXPH(ACCV, IH) do {                                                        \
    _Pragma("unroll") for (int mt = 0; mt < 4; ++mt) {                             \
      s[mt * 4 + 2 * (IH)]     += fast_exp2(ACCV[mt][2 * (IH)]);                   \
      s[mt * 4 + 2 * (IH) + 1] += fast_exp2(ACCV[mt][2 * (IH) + 1]);               \
    } } while (0)

  // STEP QQ: wait -> [fence] -> ds_read next quarter into BFL -> issue QQ+4
  //          -> 16 MFMA on BFU (loaded last step) -> EXP half of other acc
#define STEP(QQ, BFU, BFL, ACC, HALF, EACC, EH, DO_EXP, DO_READ, DO_ISSUE, WN)     \
  do {                                                                             \
    asm volatile("s_waitcnt vmcnt(" #WN ")" ::: "memory");                         \
    __builtin_amdgcn_sched_barrier(0);                                             \
    if (DO_READ) DSREAD(BFL, ((QQ) + 1) & 3);                                      \
    if (DO_ISSUE) ISSUEQ((QQ) + 4);                                                \
    __builtin_amdgcn_s_setprio(1);                                                 \
    if ((HALF) == 0) {                                                             \
      _Pragma("unroll") for (int mt = 0; mt < 4; ++mt)                             \
        ACC[mt] = __builtin_amdgcn_mfma_f32_16x16x32_bf16(afrag[mt][0], BFU[0],    \
                      negInit[mt], 0, 0, 0);                                       \
      _Pragma("unroll") for (int k = 1; k < 4; ++k)                                \
        _Pragma("unroll") for (int mt = 0; mt < 4; ++mt)                           \
          ACC[mt] = __builtin_amdgcn_mfma_f32_16x16x32_bf16(afrag[mt][k], BFU[k],  \
                        ACC[mt], 0, 0, 0);                                         \
    } else {                                                                       \
      _Pragma("unroll") for (int k = 0; k < 4; ++k)                                \
        _Pragma("unroll") for (int mt = 0; mt < 4; ++mt)                           \
          ACC[mt] = __builtin_amdgcn_mfma_f32_16x16x32_bf16(afrag[mt][4 + k],      \
                        BFU[k], ACC[mt], 0, 0, 0);                                 \
    }                                                                              \
    __builtin_amdgcn_s_setprio(0);                                                 \
    if (DO_EXP) EXPH(EACC, EH);                                                    \
  } while (0)

  // prologue: 4 quarters in flight, first quarter into bfE
  ISSUEQ(0); ISSUEQ(1); ISSUEQ(2); ISSUEQ(3);          // 16 DMAs out
  asm volatile("s_waitcnt vmcnt(12)" ::: "memory");    // q0 landed
  __builtin_amdgcn_sched_barrier(0);
  DSREAD(bfE, 0);                                      // for step 0

  // group 0 (tiles 0,1): no EXP on steps 0,1
  STEP(0, bfE, bfO, accA, 0, accB, 0, 0, 1, 1, 8);
  STEP(1, bfO, bfE, accA, 1, accB, 1, 0, 1, 1, 8);
  STEP(2, bfE, bfO, accB, 0, accA, 0, 1, 1, 1, 8);
  STEP(3, bfO, bfE, accB, 1, accA, 1, 1, 1, 1, 8);
  // groups 1..14 (quarters 4..59, all steady)
  for (int tt = 1; tt < 15; ++tt) {
    const int q0 = tt * 4;
    STEP(q0 + 0, bfE, bfO, accA, 0, accB, 0, 1, 1, 1, 8);
    STEP(q0 + 1, bfO, bfE, accA, 1, accB, 1, 1, 1, 1, 8);
    STEP(q0 + 2, bfE, bfO, accB, 0, accA, 0, 1, 1, 1, 8);
    STEP(q0 + 3, bfO, bfE, accB, 1, accA, 1, 1, 1, 1, 8);
  }
  // group 15 (quarters 60..63): drain
  STEP(60, bfE, bfO, accA, 0, accB, 0, 1, 1, 0, 8);
  STEP(61, bfO, bfE, accA, 1, accB, 1, 1, 1, 0, 4);
  STEP(62, bfE, bfO, accB, 0, accA, 0, 1, 1, 0, 0);
  STEP(63, bfO, bfE, accB, 1, accA, 1, 1, 0, 0, 0);
  EXPH(accB, 0); EXPH(accB, 1);    // last tile (31)

#undef STEP
#undef EXPH
#undef DSREAD
#undef ISSUEQ

  // ---- sum the 16 column-partials (lanes differing in low 4 bits) ----
#pragma unroll
  for (int d = 1; d < 16; d <<= 1)
#pragma unroll
    for (int e = 0; e < 16; ++e) s[e] += __shfl_xor(s[e], d, 64);
  if (r16 == 0) {
#pragma unroll
    for (int mt = 0; mt < 4; ++mt)
#pragma unroll
      for (int i = 0; i < 4; ++i)
        swS[w][mt * 16 + kg * 4 + i] = s[mt * 4 + i];
  }
  __syncthreads();

  // ---- final per-row loss + block reduce (wave 0 only) ----
  if (t < 64) {
    const float S = 1.f + swS[0][t] + swS[1][t] + swS[2][t] + swS[3][t];
    float loss = -logf(1.f / S + EPSV);
#pragma unroll
    for (int d = 1; d < 64; d <<= 1) loss += __shfl_xor(loss, d, 64);
    if (t == 0) blockSums[p] = loss;
  }
}

// ---------------------------------------------------------------------------
// Final: mean of 512 block sums / (512*64).  grid=1, block=256.
// ---------------------------------------------------------------------------
__global__ void cpl_final(const float* __restrict__ blockSums, float* __restrict__ out) {
  const int t = threadIdx.x;
  float s = blockSums[t] + blockSums[t + 256];
#pragma unroll
  for (int d = 1; d < 64; d <<= 1) s += __shfl_xor(s, d, 64);
  __shared__ float ps[4];
  if ((t & 63) == 0) ps[t >> 6] = s;
  __syncthreads();
  if (t == 0) out[0] = (ps[0] + ps[1] + ps[2] + ps[3]) * (1.f / 32768.f);
}

extern "C" void kernel_launch(void* const* d_in, const int* in_sizes, int n_in,
                              void* d_out, int out_size, void* d_ws, size_t ws_size,
                              hipStream_t stream) {
  const float* mainO = (const float*)d_in[0];
  const float* emaO  = (const float*)d_in[1];
  const float* label = (const float*)d_in[2];
  const float* negB  = (const float*)d_in[3];
  const float* posB  = (const float*)d_in[4];
  float* out = (float*)d_out;

  char* ws = (char*)d_ws;
  float*  blockSums = (float*)ws;                        // 2 KiB
  int*    flags     = (int*)(ws + 2048);                 // 2 KiB
  ushort* bankN     = (ushort*)(ws + 4096);              // 1 MiB
  ushort* bankP     = (ushort*)(ws + 4096 + 1048576);    // 1 MiB
  float*  posDot    = (float*)(ws + 4096 + 2097152);     // 128 KiB
  ushort* Apk       = (ushort*)(ws + 4096 + 2097152 + 131072);  // 16.78 MiB

  hipLaunchKernelGGL(cpl_prep, dim3(1088), dim3(256), 0, stream,
                     mainO, emaO, label, negB, posB, Apk, posDot, flags, bankN, bankP);
  hipLaunchKernelGGL(cpl_main, dim3(512), dim3(256), 0, stream,
                     Apk, posDot, bankN, bankP, flags, blockSums);
  hipLaunchKernelGGL(cpl_final, dim3(1), dim3(256), 0, stream, blockSums, out);
}

// Round 13
// 58.647 us; speedup vs baseline: 1.0634x; 1.0634x over previous
//
#include <hip/hip_runtime.h>

typedef __attribute__((ext_vector_type(8))) short bf16x8;
typedef __attribute__((ext_vector_type(4))) float f32x4;

#define EPSV 1e-5f
// (1/TEMP) * log2(e),  TEMP = 0.5  -> exp2-domain scale
#define SCALE 2.885390081777927f

// Must be the builtin — raw inline-asm v_exp_f32 lacks the TRANS-pipe hazard
// nop (asm is opaque to the hazard recognizer) and returns garbage (R4).
__device__ __forceinline__ float fast_exp2(float x) { return __builtin_amdgcn_exp2f(x); }

__device__ __forceinline__ ushort f32_to_bf16(float f) {
  union { float f; unsigned u; } cv; cv.f = f;
  unsigned u = cv.u;
  u += 0x7FFFu + ((u >> 16) & 1u);   // round-to-nearest-even
  return (ushort)(u >> 16);
}

// ---------------------------------------------------------------------------
// Packed bank layout (bf16, pre-scaled by SCALE):
//   col-tile ct = col>>4, r16 = col&15; channel c: ks = c>>5, kg = (c>>3)&3.
//   byte addr = ct*8192 + ks*1024 + kg*256 + r16*16 + (c&7)*2
// Quarter q (4 KB) = (ct = q>>1, ks-half = q&1). A wave's 512-col range is a
// linear 256 KB stream of 64 quarters.
// ---------------------------------------------------------------------------

// ---------------------------------------------------------------------------
// Fused prep kernel, grid = 512 + 512 + 64 = 1088 blocks, 256 threads.
// ---------------------------------------------------------------------------
__global__ __launch_bounds__(256) void cpl_prep(
    const float* __restrict__ mainO, const float* __restrict__ emaO,
    const float* __restrict__ label, const float* __restrict__ negB,
    const float* __restrict__ posB,
    ushort* __restrict__ Apk, float* __restrict__ posDot,
    int* __restrict__ flags, ushort* __restrict__ bankN, ushort* __restrict__ bankP)
{
  __shared__ ushort shU[64 * 256];   // 32 KiB
  __shared__ float  shF[4][64];
  const int bid = blockIdx.x;
  const int t = threadIdx.x;

  if (bid < 512) {
    // ---- anchor pack + pos dot: block = (b, y) ----
    const int b = bid >> 6, y = bid & 63;
    const int cg = t >> 4;            // c-offset 0..15
    const int x4 = t & 15;            // float4 index along W
    const float* mB = mainO + (((size_t)b * 256 + cg) * 64 + y) * 64 + x4 * 4;
    const float* eB = emaO  + (((size_t)b * 256 + cg) * 64 + y) * 64 + x4 * 4;
    float4 acc4 = make_float4(0.f, 0.f, 0.f, 0.f);
#pragma unroll
    for (int pass = 0; pass < 16; ++pass) {
      const int c = pass * 16 + cg;
      const float4 mv = *(const float4*)(mB + (size_t)pass * 16 * 4096);
      const float4 ev = *(const float4*)(eB + (size_t)pass * 16 * 4096);
      acc4.x += mv.x * ev.x; acc4.y += mv.y * ev.y;
      acc4.z += mv.z * ev.z; acc4.w += mv.w * ev.w;
      const float vals[4] = {mv.x, mv.y, mv.z, mv.w};
#pragma unroll
      for (int j = 0; j < 4; ++j) {
        const int x = x4 * 4 + j;
        shU[x * 256 + (c ^ ((x & 7) << 3))] = f32_to_bf16(vals[j]);
      }
    }
    // reduce pos partials over c-groups (cg bit0 = lane bit4, bit1 = lane bit5)
    acc4.x += __shfl_xor(acc4.x, 16, 64); acc4.y += __shfl_xor(acc4.y, 16, 64);
    acc4.z += __shfl_xor(acc4.z, 16, 64); acc4.w += __shfl_xor(acc4.w, 16, 64);
    acc4.x += __shfl_xor(acc4.x, 32, 64); acc4.y += __shfl_xor(acc4.y, 32, 64);
    acc4.z += __shfl_xor(acc4.z, 32, 64); acc4.w += __shfl_xor(acc4.w, 32, 64);
    if ((t & 63) < 16) *(float4*)&shF[t >> 6][(t & 15) * 4] = acc4;
    __syncthreads();
    // write packed anchors (coalesced b128)
#pragma unroll
    for (int it = 0; it < 8; ++it) {
      const int lin = it * 256 + t;          // 0..2047
      const int x = lin >> 5, c8 = lin & 31;
      const uint4 v = *(const uint4*)&shU[x * 256 + ((c8 * 8) ^ ((x & 7) << 3))];
      const int p = b * 64 + ((y >> 3) << 3) + (x >> 3);
      const int n = ((y & 7) << 3) + (x & 7);
      *(uint4*)&Apk[((size_t)p * 64 + n) * 256 + c8 * 8] = v;
    }
    if (t < 64) {
      const float pv = shF[0][t] + shF[1][t] + shF[2][t] + shF[3][t];
      const int p = b * 64 + ((y >> 3) << 3) + (t >> 3);
      const int n = ((y & 7) << 3) + (t & 7);
      posDot[p * 64 + n] = pv;
    }
  } else if (bid < 1024) {
    // ---- label mean -> flag ----
    const int p = bid - 512;
    const int b = p >> 6, pj = (p >> 3) & 7, pk = p & 7;
    const size_t base = ((size_t)b * 256 + pj * 32) * 256 + pk * 32;
    float s = 0.f;
#pragma unroll
    for (int i = 0; i < 4; ++i) {
      const int e = t * 4 + i;               // 0..1023, r=e>>5, cc=e&31
      s += label[base + (size_t)(e >> 5) * 256 + (e & 31)];
    }
#pragma unroll
    for (int d = 1; d < 64; d <<= 1) s += __shfl_xor(s, d, 64);
    if ((t & 63) == 0) shF[0][t >> 6] = s;
    __syncthreads();
    if (t == 0)
      flags[p] = ((shF[0][0] + shF[0][1] + shF[0][2] + shF[0][3]) * (1.f / 1024.f) < 0.1f) ? 1 : 0;
  } else {
    // ---- bank repack (pre-scaled by SCALE) into the packed tile layout ----
    const int bb = bid - 1024;
    const float* src = (bb < 32 ? negB : posB) + (size_t)(bb & 31) * 16384;
    ushort* dst = (bb < 32 ? bankN : bankP) + (size_t)(bb & 31) * 16384;
#pragma unroll 8
    for (int it = 0; it < 64; ++it) {
      const int lin = it * 256 + t;          // [c][posi] linear, coalesced read
      const int c = lin >> 6, posi = lin & 63;
      shU[(posi * 256 + c) ^ ((posi & 31) << 1)] = f32_to_bf16(src[lin] * SCALE);
    }
    __syncthreads();
    unsigned* dst32 = (unsigned*)dst;        // 8192 uints per slab
#pragma unroll 8
    for (int it = 0; it < 32; ++it) {
      const int pt = it >> 3, ks = it & 7;
      const int kg = t >> 6, r16 = (t >> 2) & 15, bw = t & 3;
      const int posi = pt * 16 + r16;
      const int c = ks * 32 + kg * 8 + bw * 2;
      const unsigned v = *(const unsigned*)&shU[(posi * 256 + c) ^ ((posi & 31) << 1)];
      dst32[pt * 2048 + ks * 256 + kg * 64 + r16 * 4 + bw] = v;
    }
  }
}

// ---------------------------------------------------------------------------
// Main kernel: grid=512 (one patch), block=256 (4 independent waves).
// B streamed DIRECTLY to registers via global_load_dwordx4 (L2 pipe, ~56 B/cy
// per CU) instead of global_load_lds (measured ~20 B/cy ceiling). 3-deep
// register ring of 2 KB quarter-buffers (16 VGPR each): step n issues loads
// for quarter n+2 and MFMAs on quarter n (loaded 2 steps earlier -> counted
// vmcnt(8) auto-inserted by compiler; L2 latency hidden). No LDS staging, no
// barriers in the loop. Per-block EVEN phase rotation (parity-preserving —
// odd rotation mismatched ks-halves, fixed from R11/R12).
// ---------------------------------------------------------------------------
__global__ __launch_bounds__(256, 2) void cpl_main(
    const ushort* __restrict__ Apk, const float* __restrict__ posDot,
    const ushort* __restrict__ bankN, const ushort* __restrict__ bankP,
    const int* __restrict__ flags, float* __restrict__ blockSums)
{
  __shared__ float swS[4][64];

  const int p = blockIdx.x;
  const int t = threadIdx.x;
  const int l = t & 63, w = t >> 6;
  const int r16 = l & 15, kg = l >> 4;
  const int qph = (p * 22) & 63;      // EVEN phase: preserves quarter parity

  const char* bankB = (const char*)(flags[p] ? bankP : bankN);
  const char* wsrc = bankB + (size_t)w * 262144;     // wave's 512-col stream
  const int lofs2 = kg * 256 + r16 * 16;             // lane offset in a quarter

  // ---- A fragments: lane l holds A[mt*16+(l&15)][ks*32+(l>>4)*8 + 0..7] ----
  const ushort* Ab = Apk + (size_t)p * 16384;
  bf16x8 afrag[4][8];
#pragma unroll
  for (int mt = 0; mt < 4; ++mt)
#pragma unroll
    for (int ks = 0; ks < 8; ++ks)
      afrag[mt][ks] = *(const bf16x8*)(Ab + (mt * 16 + r16) * 256 + ks * 32 + kg * 8);
#pragma unroll
  for (int mt = 0; mt < 4; ++mt)
#pragma unroll
    for (int ks = 0; ks < 8; ++ks)
      asm volatile("" : "+v"(afrag[mt][ks]));

  // per-lane -pos2 init in REGISTERS (row = mt*16 + kg*4 + i), direct global
  f32x4 negInit[4];
#pragma unroll
  for (int mt = 0; mt < 4; ++mt) {
    f32x4 v = *(const f32x4*)(posDot + (size_t)p * 64 + mt * 16 + kg * 4);
#pragma unroll
    for (int i = 0; i < 4; ++i) negInit[mt][i] = -v[i] * SCALE;
  }
#pragma unroll
  for (int mt = 0; mt < 4; ++mt) asm volatile("" : "+v"(negInit[mt]));

  float s[16];
#pragma unroll
  for (int e = 0; e < 16; ++e) s[e] = 0.f;

  f32x4 acc[4];
  bf16x8 bf0[4], bf1[4], bf2[4];     // 3-deep ring, 16 VGPR each

#define GLOAD(BF, QQ) do {                                                         \
    const char* g_ = wsrc + (size_t)((((QQ) + qph) & 63)) * 4096 + lofs2;          \
    _Pragma("unroll") for (int k = 0; k < 4; ++k)                                  \
      BF[k] = *(const bf16x8*)(g_ + k * 1024);                                     \
  } while (0)

#define MFMA16(BFU, HALF) do {                                                     \
    if ((HALF) == 0) {                                                             \
      _Pragma("unroll") for (int mt = 0; mt < 4; ++mt)                             \
        acc[mt] = __builtin_amdgcn_mfma_f32_16x16x32_bf16(afrag[mt][0], BFU[0],    \
                      negInit[mt], 0, 0, 0);                                       \
      _Pragma("unroll") for (int k = 1; k < 4; ++k)                                \
        _Pragma("unroll") for (int mt = 0; mt < 4; ++mt)                           \
          acc[mt] = __builtin_amdgcn_mfma_f32_16x16x32_bf16(afrag[mt][k], BFU[k],  \
                        acc[mt], 0, 0, 0);                                         \
    } else {                                                                       \
      _Pragma("unroll") for (int k = 0; k < 4; ++k)                                \
        _Pragma("unroll") for (int mt = 0; mt < 4; ++mt)                           \
          acc[mt] = __builtin_amdgcn_mfma_f32_16x16x32_bf16(afrag[mt][4 + k],      \
                        BFU[k], acc[mt], 0, 0, 0);                                 \
    } } while (0)

#define EXPACC() do {                                                              \
    _Pragma("unroll") for (int mt = 0; mt < 4; ++mt)                               \
      _Pragma("unroll") for (int i = 0; i < 4; ++i)                                \
        s[mt * 4 + i] += fast_exp2(acc[mt][i]); } while (0)

  // STEP n: issue loads for quarter n+2 into BFL, MFMA on BFU (= quarter n,
  // loaded 2 steps ago -> compiler emits counted vmcnt(8)), EXP after odd steps.
#define STEP(QQ, BFU, BFL, HALF, DO_LOAD, DO_EXP) do {                             \
    if (DO_LOAD) GLOAD(BFL, (QQ) + 2);                                            \
    __builtin_amdgcn_sched_barrier(0);                                             \
    __builtin_amdgcn_s_setprio(1);                                                 \
    MFMA16(BFU, HALF);                                                             \
    __builtin_amdgcn_s_setprio(0);                                                 \
    if (DO_EXP) EXPACC();                                                          \
    __builtin_amdgcn_sched_barrier(0);                                             \
  } while (0)

  // prologue: quarters 0,1 in flight
  GLOAD(bf0, 0);
  GLOAD(bf1, 1);
  // steps 0..59: period-6 pattern (buffer = n%3, half = n&1)
  for (int g6 = 0; g6 < 10; ++g6) {
    const int n0 = g6 * 6;
    STEP(n0 + 0, bf0, bf2, 0, 1, 0);
    STEP(n0 + 1, bf1, bf0, 1, 1, 1);
    STEP(n0 + 2, bf2, bf1, 0, 1, 0);
    STEP(n0 + 3, bf0, bf2, 1, 1, 1);
    STEP(n0 + 4, bf1, bf0, 0, 1, 0);
    STEP(n0 + 5, bf2, bf1, 1, 1, 1);
  }
  // steps 60..63 (loads for q62, q63 then drain)
  STEP(60, bf0, bf2, 0, 1, 0);
  STEP(61, bf1, bf0, 1, 1, 1);
  STEP(62, bf2, bf2, 0, 0, 0);
  STEP(63, bf0, bf0, 1, 0, 1);

#undef STEP
#undef EXPACC
#undef MFMA16
#undef GLOAD

  // ---- sum the 16 column-partials (lanes differing in low 4 bits) ----
#pragma unroll
  for (int d = 1; d < 16; d <<= 1)
#pragma unroll
    for (int e = 0; e < 16; ++e) s[e] += __shfl_xor(s[e], d, 64);
  if (r16 == 0) {
#pragma unroll
    for (int mt = 0; mt < 4; ++mt)
#pragma unroll
      for (int i = 0; i < 4; ++i)
        swS[w][mt * 16 + kg * 4 + i] = s[mt * 4 + i];
  }
  __syncthreads();

  // ---- final per-row loss + block reduce (wave 0 only) ----
  if (t < 64) {
    const float S = 1.f + swS[0][t] + swS[1][t] + swS[2][t] + swS[3][t];
    float loss = -logf(1.f / S + EPSV);
#pragma unroll
    for (int d = 1; d < 64; d <<= 1) loss += __shfl_xor(loss, d, 64);
    if (t == 0) blockSums[p] = loss;
  }
}

// ---------------------------------------------------------------------------
// Final: mean of 512 block sums / (512*64).  grid=1, block=256.
// ---------------------------------------------------------------------------
__global__ void cpl_final(const float* __restrict__ blockSums, float* __restrict__ out) {
  const int t = threadIdx.x;
  float s = blockSums[t] + blockSums[t + 256];
#pragma unroll
  for (int d = 1; d < 64; d <<= 1) s += __shfl_xor(s, d, 64);
  __shared__ float ps[4];
  if ((t & 63) == 0) ps[t >> 6] = s;
  __syncthreads();
  if (t == 0) out[0] = (ps[0] + ps[1] + ps[2] + ps[3]) * (1.f / 32768.f);
}

extern "C" void kernel_launch(void* const* d_in, const int* in_sizes, int n_in,
                              void* d_out, int out_size, void* d_ws, size_t ws_size,
                              hipStream_t stream) {
  const float* mainO = (const float*)d_in[0];
  const float* emaO  = (const float*)d_in[1];
  const float* label = (const float*)d_in[2];
  const float* negB  = (const float*)d_in[3];
  const float* posB  = (const float*)d_in[4];
  float* out = (float*)d_out;

  char* ws = (char*)d_ws;
  float*  blockSums = (float*)ws;                        // 2 KiB
  int*    flags     = (int*)(ws + 2048);                 // 2 KiB
  ushort* bankN     = (ushort*)(ws + 4096);              // 1 MiB
  ushort* bankP     = (ushort*)(ws + 4096 + 1048576);    // 1 MiB
  float*  posDot    = (float*)(ws + 4096 + 2097152);     // 128 KiB
  ushort* Apk       = (ushort*)(ws + 4096 + 2097152 + 131072);  // 16.78 MiB

  hipLaunchKernelGGL(cpl_prep, dim3(1088), dim3(256), 0, stream,
                     mainO, emaO, label, negB, posB, Apk, posDot, flags, bankN, bankP);
  hipLaunchKernelGGL(cpl_main, dim3(512), dim3(256), 0, stream,
                     Apk, posDot, bankN, bankP, flags, blockSums);
  hipLaunchKernelGGL(cpl_final, dim3(1), dim3(256), 0, stream, blockSums, out);
}

// Round 14
// 49.122 us; speedup vs baseline: 1.2696x; 1.1939x over previous
//
#include <hip/hip_runtime.h>

typedef __attribute__((ext_vector_type(2))) long long2v;
typedef __attribute__((ext_vector_type(4))) float f32x4;

#define EPSV 1e-5f
// (1/TEMP) * log2(e),  TEMP = 0.5  -> exp2-domain scale
#define SCALE 2.885390081777927f

// Must be the builtin — raw inline-asm v_exp_f32 lacks the TRANS-pipe hazard
// nop (asm is opaque to the hazard recognizer) and returns garbage (R4).
__device__ __forceinline__ float fast_exp2(float x) { return __builtin_amdgcn_exp2f(x); }

// f32 -> OCP e4m3fn byte (hardware converter; saturates at +-448)
__device__ __forceinline__ unsigned char f32_to_fp8(float f) {
  return (unsigned char)(__builtin_amdgcn_cvt_pk_fp8_f32(f, f, 0, false) & 0xff);
}

// ---------------------------------------------------------------------------
// FP8 packed bank layout (pre-scaled by SCALE). Global col col, channel k:
//   ct = col>>4, r16 = col&15; quarter qK = k>>7 (K-half);
//   within quarter: pair = (k>>6)&1, half = (k>>5)&1, kg = (k>>3)&3, b = k&7
//   byte = ct*4096 + qK*2048 + pair*1024 + kg*256 + r16*16 + half*8 + b
// Quarter q (2 KB) = (ct = q>>1, qK = q&1); a wave's 512-col range is a linear
// 128 KB stream of 64 quarters. Lane (kg,r16) reads 16 B at +pair*1024 holding
// MFMA B-frags ks_local = 2*pair (low 8 B) and 2*pair+1 (high 8 B).
// Apk (fp8 anchors): byte = p*16384 + row*256 + k.
// ---------------------------------------------------------------------------

// ---------------------------------------------------------------------------
// Fused prep kernel, grid = 512 + 512 + 64 = 1088 blocks, 256 threads.
// ---------------------------------------------------------------------------
__global__ __launch_bounds__(256) void cpl_prep(
    const float* __restrict__ mainO, const float* __restrict__ emaO,
    const float* __restrict__ label, const float* __restrict__ negB,
    const float* __restrict__ posB,
    unsigned char* __restrict__ Apk, float* __restrict__ posDot,
    int* __restrict__ flags, unsigned char* __restrict__ bankN,
    unsigned char* __restrict__ bankP)
{
  __shared__ __align__(16) unsigned char shU[64 * 256];   // 16 KiB
  __shared__ float shF[4][64];
  const int bid = blockIdx.x;
  const int t = threadIdx.x;

  if (bid < 512) {
    // ---- anchor pack (fp8) + pos dot: block = (b, y) ----
    const int b = bid >> 6, y = bid & 63;
    const int cg = t >> 4;            // c-offset 0..15
    const int x4 = t & 15;            // float4 index along W
    const float* mB = mainO + (((size_t)b * 256 + cg) * 64 + y) * 64 + x4 * 4;
    const float* eB = emaO  + (((size_t)b * 256 + cg) * 64 + y) * 64 + x4 * 4;
    float4 acc4 = make_float4(0.f, 0.f, 0.f, 0.f);
#pragma unroll
    for (int pass = 0; pass < 16; ++pass) {
      const int c = pass * 16 + cg;
      const float4 mv = *(const float4*)(mB + (size_t)pass * 16 * 4096);
      const float4 ev = *(const float4*)(eB + (size_t)pass * 16 * 4096);
      acc4.x += mv.x * ev.x; acc4.y += mv.y * ev.y;
      acc4.z += mv.z * ev.z; acc4.w += mv.w * ev.w;
      const float vals[4] = {mv.x, mv.y, mv.z, mv.w};
#pragma unroll
      for (int j = 0; j < 4; ++j) {
        const int x = x4 * 4 + j;
        shU[x * 256 + (c ^ ((x & 7) << 4))] = f32_to_fp8(vals[j]);
      }
    }
    // reduce pos partials over c-groups (cg bit0 = lane bit4, bit1 = lane bit5)
    acc4.x += __shfl_xor(acc4.x, 16, 64); acc4.y += __shfl_xor(acc4.y, 16, 64);
    acc4.z += __shfl_xor(acc4.z, 16, 64); acc4.w += __shfl_xor(acc4.w, 16, 64);
    acc4.x += __shfl_xor(acc4.x, 32, 64); acc4.y += __shfl_xor(acc4.y, 32, 64);
    acc4.z += __shfl_xor(acc4.z, 32, 64); acc4.w += __shfl_xor(acc4.w, 32, 64);
    if ((t & 63) < 16) *(float4*)&shF[t >> 6][(t & 15) * 4] = acc4;
    __syncthreads();
    // write packed fp8 anchors (coalesced b128)
#pragma unroll
    for (int it = 0; it < 4; ++it) {
      const int lin = it * 256 + t;          // 0..1023
      const int x = lin >> 4, c16 = lin & 15;
      const uint4 v = *(const uint4*)&shU[x * 256 + ((c16 * 16) ^ ((x & 7) << 4))];
      const int p = b * 64 + ((y >> 3) << 3) + (x >> 3);
      const int n = ((y & 7) << 3) + (x & 7);
      *(uint4*)&Apk[(size_t)p * 16384 + n * 256 + c16 * 16] = v;
    }
    if (t < 64) {
      const float pv = shF[0][t] + shF[1][t] + shF[2][t] + shF[3][t];
      const int p = b * 64 + ((y >> 3) << 3) + (t >> 3);
      const int n = ((y & 7) << 3) + (t & 7);
      posDot[p * 64 + n] = pv;
    }
  } else if (bid < 1024) {
    // ---- label mean -> flag ----
    const int p = bid - 512;
    const int b = p >> 6, pj = (p >> 3) & 7, pk = p & 7;
    const size_t base = ((size_t)b * 256 + pj * 32) * 256 + pk * 32;
    float s = 0.f;
#pragma unroll
    for (int i = 0; i < 4; ++i) {
      const int e = t * 4 + i;               // 0..1023, r=e>>5, cc=e&31
      s += label[base + (size_t)(e >> 5) * 256 + (e & 31)];
    }
#pragma unroll
    for (int d = 1; d < 64; d <<= 1) s += __shfl_xor(s, d, 64);
    if ((t & 63) == 0) shF[0][t >> 6] = s;
    __syncthreads();
    if (t == 0)
      flags[p] = ((shF[0][0] + shF[0][1] + shF[0][2] + shF[0][3]) * (1.f / 1024.f) < 0.1f) ? 1 : 0;
  } else {
    // ---- bank repack (fp8, pre-scaled by SCALE) into packed tile layout ----
    const int bb = bid - 1024;
    const float* src = (bb < 32 ? negB : posB) + (size_t)(bb & 31) * 16384;
    unsigned char* dst = (bb < 32 ? bankN : bankP) + (size_t)(bb & 31) * 16384;
#pragma unroll 8
    for (int it = 0; it < 64; ++it) {
      const int lin = it * 256 + t;          // [c][posi] linear, coalesced read
      const int c = lin >> 6, posi = lin & 63;
      shU[posi * 256 + (c ^ ((posi & 7) << 3))] = f32_to_fp8(src[lin] * SCALE);
    }
    __syncthreads();
#pragma unroll
    for (int it = 0; it < 4; ++it) {         // ct_local = it
      const int qK = (t >> 7) & 1, pair = (t >> 6) & 1;
      const int kg = (t >> 4) & 3, r16 = t & 15;
      const int posi = it * 16 + r16;
      const int kb = qK * 128 + pair * 64 + kg * 8;
      const int swz = (posi & 7) << 3;
      const unsigned long long lo = *(const unsigned long long*)&shU[posi * 256 + (kb ^ swz)];
      const unsigned long long hi = *(const unsigned long long*)&shU[posi * 256 + ((kb + 32) ^ swz)];
      long2v v; v[0] = (long)lo; v[1] = (long)hi;
      *(long2v*)(dst + it * 4096 + qK * 2048 + pair * 1024 + kg * 256 + r16 * 16) = v;
    }
  }
}

// ---------------------------------------------------------------------------
// Main kernel: grid=512 (one patch), block=256 (4 independent waves), FP8.
// B streamed directly to registers (2 x dwordx4 per 2 KB quarter) through an
// 8-DEEP register ring (14 loads in flight -> latency term L/7); MFMA
// 16x16x32_fp8_fp8 (bf16 rate, half the operand bytes -> 2x arithmetic
// intensity vs bf16 against the measured ~22 B/cy/CU B-delivery ceiling).
// ---------------------------------------------------------------------------
__global__ __launch_bounds__(256, 2) void cpl_main(
    const unsigned char* __restrict__ Apk, const float* __restrict__ posDot,
    const unsigned char* __restrict__ bankN, const unsigned char* __restrict__ bankP,
    const int* __restrict__ flags, float* __restrict__ blockSums)
{
  __shared__ float swS[4][64];

  const int p = blockIdx.x;
  const int t = threadIdx.x;
  const int l = t & 63, w = t >> 6;
  const int r16 = l & 15, kg = l >> 4;
  const int qph = (p * 22) & 63;      // EVEN phase: preserves quarter parity

  const unsigned char* bankB = flags[p] ? bankP : bankN;
  const unsigned char* wsrc = bankB + (size_t)w * 131072;   // wave's 512-col stream
  const int lofs = kg * 256 + r16 * 16;

  // ---- A fragments (fp8): lane l holds A[mt*16+r16][ks*32+kg*8 .. +7] ----
  const unsigned char* Ab = Apk + (size_t)p * 16384;
  long long afrag[4][8];
#pragma unroll
  for (int mt = 0; mt < 4; ++mt)
#pragma unroll
    for (int ks = 0; ks < 8; ++ks)
      afrag[mt][ks] = *(const long long*)(Ab + (mt * 16 + r16) * 256 + ks * 32 + kg * 8);
#pragma unroll
  for (int mt = 0; mt < 4; ++mt)
#pragma unroll
    for (int ks = 0; ks < 8; ++ks)
      asm volatile("" : "+v"(afrag[mt][ks]));

  // per-lane -pos2 init in REGISTERS (row = mt*16 + kg*4 + i)
  f32x4 negInit[4];
#pragma unroll
  for (int mt = 0; mt < 4; ++mt) {
    f32x4 v = *(const f32x4*)(posDot + (size_t)p * 64 + mt * 16 + kg * 4);
#pragma unroll
    for (int i = 0; i < 4; ++i) negInit[mt][i] = -v[i] * SCALE;
  }
#pragma unroll
  for (int mt = 0; mt < 4; ++mt) asm volatile("" : "+v"(negInit[mt]));

  float s[16];
#pragma unroll
  for (int e = 0; e < 16; ++e) s[e] = 0.f;

  f32x4 acc[4];
  long2v A0, A1, B0, B1, C0, C1, D0, D1, E0, E1, F0, F1, G0, G1, H0, H1;

#define GLOAD(P0, P1, QQ) do {                                                     \
    const unsigned char* g_ = wsrc + (size_t)((((QQ) + qph) & 63)) * 2048 + lofs;  \
    P0 = *(const long2v*)g_;                                                       \
    P1 = *(const long2v*)(g_ + 1024);                                              \
  } while (0)

#define MFMA16(P0, P1, HALF) do {                                                  \
    if ((HALF) == 0) {                                                             \
      _Pragma("unroll") for (int mt = 0; mt < 4; ++mt)                             \
        acc[mt] = __builtin_amdgcn_mfma_f32_16x16x32_fp8_fp8(afrag[mt][0], P0[0],  \
                      negInit[mt], 0, 0, 0);                                       \
      _Pragma("unroll") for (int mt = 0; mt < 4; ++mt)                             \
        acc[mt] = __builtin_amdgcn_mfma_f32_16x16x32_fp8_fp8(afrag[mt][1], P0[1],  \
                      acc[mt], 0, 0, 0);                                           \
      _Pragma("unroll") for (int mt = 0; mt < 4; ++mt)                             \
        acc[mt] = __builtin_amdgcn_mfma_f32_16x16x32_fp8_fp8(afrag[mt][2], P1[0],  \
                      acc[mt], 0, 0, 0);                                           \
      _Pragma("unroll") for (int mt = 0; mt < 4; ++mt)                             \
        acc[mt] = __builtin_amdgcn_mfma_f32_16x16x32_fp8_fp8(afrag[mt][3], P1[1],  \
                      acc[mt], 0, 0, 0);                                           \
    } else {                                                                       \
      _Pragma("unroll") for (int mt = 0; mt < 4; ++mt)                             \
        acc[mt] = __builtin_amdgcn_mfma_f32_16x16x32_fp8_fp8(afrag[mt][4], P0[0],  \
                      acc[mt], 0, 0, 0);                                           \
      _Pragma("unroll") for (int mt = 0; mt < 4; ++mt)                             \
        acc[mt] = __builtin_amdgcn_mfma_f32_16x16x32_fp8_fp8(afrag[mt][5], P0[1],  \
                      acc[mt], 0, 0, 0);                                           \
      _Pragma("unroll") for (int mt = 0; mt < 4; ++mt)                             \
        acc[mt] = __builtin_amdgcn_mfma_f32_16x16x32_fp8_fp8(afrag[mt][6], P1[0],  \
                      acc[mt], 0, 0, 0);                                           \
      _Pragma("unroll") for (int mt = 0; mt < 4; ++mt)                             \
        acc[mt] = __builtin_amdgcn_mfma_f32_16x16x32_fp8_fp8(afrag[mt][7], P1[1],  \
                      acc[mt], 0, 0, 0);                                           \
    } } while (0)

#define EXPACC() do {                                                              \
    _Pragma("unroll") for (int mt = 0; mt < 4; ++mt)                               \
      _Pragma("unroll") for (int i = 0; i < 4; ++i)                                \
        s[mt * 4 + i] += fast_exp2(acc[mt][i]); } while (0)

  // STEP n: load quarter n+7 into the buffer consumed last step; MFMA on the
  // buffer loaded 7 steps ago (compiler emits counted vmcnt); EXP after odd.
#define STEP(QQ, U0, U1, L0, L1, HALF, DO_LOAD, DO_EXP) do {                       \
    if (DO_LOAD) GLOAD(L0, L1, (QQ) + 7);                                          \
    __builtin_amdgcn_sched_barrier(0);                                             \
    __builtin_amdgcn_s_setprio(1);                                                 \
    MFMA16(U0, U1, HALF);                                                          \
    __builtin_amdgcn_s_setprio(0);                                                 \
    if (DO_EXP) EXPACC();                                                          \
    __builtin_amdgcn_sched_barrier(0);                                             \
  } while (0)

  // prologue: quarters 0..6 in flight (14 loads)
  GLOAD(A0, A1, 0); GLOAD(B0, B1, 1); GLOAD(C0, C1, 2); GLOAD(D0, D1, 3);
  GLOAD(E0, E1, 4); GLOAD(F0, F1, 5); GLOAD(G0, G1, 6);

  for (int g = 0; g < 7; ++g) {
    const int n0 = g * 8;
    STEP(n0 + 0, A0, A1, H0, H1, 0, 1, 0);
    STEP(n0 + 1, B0, B1, A0, A1, 1, 1, 1);
    STEP(n0 + 2, C0, C1, B0, B1, 0, 1, 0);
    STEP(n0 + 3, D0, D1, C0, C1, 1, 1, 1);
    STEP(n0 + 4, E0, E1, D0, D1, 0, 1, 0);
    STEP(n0 + 5, F0, F1, E0, E1, 1, 1, 1);
    STEP(n0 + 6, G0, G1, F0, F1, 0, 1, 0);
    STEP(n0 + 7, H0, H1, G0, G1, 1, 1, 1);
  }
  // final group: step 56 loads quarter 63, then drain
  STEP(56, A0, A1, H0, H1, 0, 1, 0);
  STEP(57, B0, B1, A0, A1, 1, 0, 1);
  STEP(58, C0, C1, B0, B1, 0, 0, 0);
  STEP(59, D0, D1, C0, C1, 1, 0, 1);
  STEP(60, E0, E1, D0, D1, 0, 0, 0);
  STEP(61, F0, F1, E0, E1, 1, 0, 1);
  STEP(62, G0, G1, F0, F1, 0, 0, 0);
  STEP(63, H0, H1, G0, G1, 1, 0, 1);

#undef STEP
#undef EXPACC
#undef MFMA16
#undef GLOAD

  // ---- sum the 16 column-partials (lanes differing in low 4 bits) ----
#pragma unroll
  for (int d = 1; d < 16; d <<= 1)
#pragma unroll
    for (int e = 0; e < 16; ++e) s[e] += __shfl_xor(s[e], d, 64);
  if (r16 == 0) {
#pragma unroll
    for (int mt = 0; mt < 4; ++mt)
#pragma unroll
      for (int i = 0; i < 4; ++i)
        swS[w][mt * 16 + kg * 4 + i] = s[mt * 4 + i];
  }
  __syncthreads();

  // ---- final per-row loss + block reduce (wave 0 only) ----
  if (t < 64) {
    const float S = 1.f + swS[0][t] + swS[1][t] + swS[2][t] + swS[3][t];
    float loss = -logf(1.f / S + EPSV);
#pragma unroll
    for (int d = 1; d < 64; d <<= 1) loss += __shfl_xor(loss, d, 64);
    if (t == 0) blockSums[p] = loss;
  }
}

// ---------------------------------------------------------------------------
// Final: mean of 512 block sums / (512*64).  grid=1, block=256.
// ---------------------------------------------------------------------------
__global__ void cpl_final(const float* __restrict__ blockSums, float* __restrict__ out) {
  const int t = threadIdx.x;
  float s = blockSums[t] + blockSums[t + 256];
#pragma unroll
  for (int d = 1; d < 64; d <<= 1) s += __shfl_xor(s, d, 64);
  __shared__ float ps[4];
  if ((t & 63) == 0) ps[t >> 6] = s;
  __syncthreads();
  if (t == 0) out[0] = (ps[0] + ps[1] + ps[2] + ps[3]) * (1.f / 32768.f);
}

extern "C" void kernel_launch(void* const* d_in, const int* in_sizes, int n_in,
                              void* d_out, int out_size, void* d_ws, size_t ws_size,
                              hipStream_t stream) {
  const float* mainO = (const float*)d_in[0];
  const float* emaO  = (const float*)d_in[1];
  const float* label = (const float*)d_in[2];
  const float* negB  = (const float*)d_in[3];
  const float* posB  = (const float*)d_in[4];
  float* out = (float*)d_out;

  char* ws = (char*)d_ws;
  float*         blockSums = (float*)ws;                          // 2 KiB
  int*           flags     = (int*)(ws + 2048);                   // 2 KiB
  unsigned char* bankN     = (unsigned char*)(ws + 4096);         // 512 KiB
  unsigned char* bankP     = (unsigned char*)(ws + 528384);       // 512 KiB
  float*         posDot    = (float*)(ws + 1052672);              // 128 KiB
  unsigned char* Apk       = (unsigned char*)(ws + 1183744);      // 8 MiB

  hipLaunchKernelGGL(cpl_prep, dim3(1088), dim3(256), 0, stream,
                     mainO, emaO, label, negB, posB, Apk, posDot, flags, bankN, bankP);
  hipLaunchKernelGGL(cpl_main, dim3(512), dim3(256), 0, stream,
                     Apk, posDot, bankN, bankP, flags, blockSums);
  hipLaunchKernelGGL(cpl_final, dim3(1), dim3(256), 0, stream, blockSums, out);
}